// Round 3
// baseline (286.032 us; speedup 1.0000x reference)
//
#include <hip/hip_runtime.h>
#include <hip/hip_bf16.h>

// B=4, N=2048, F=512, INTERNAL=256. adj int32.
// Inputs: f32 (runtime-verified via k_detect; bf16 fallback kept).
// Outputs: f32 (reference output dtype): [gelu 4*2048*512 | attention 4*2048*2048].

#define B_ 4
#define N_ 2048
#define F_ 512
#define ALPHA_ 0.2f
#define NEG_INF_ -9000000000000000.0f
#define EPS_LN_ 1e-5f

typedef __attribute__((ext_vector_type(8))) short bf16x8;
typedef __attribute__((ext_vector_type(4))) float f32x4;

// ---- workspace layout (bytes), overlays: Wht over hbf (dead after gemm1), HP over Wh ----
#define HBF_OFF   0           // bf16 [8192][512]  (8388608)
#define WHT_OFF   0           // bf16 [4][512][2048] (8388608) after gemm1
#define WT_OFF    8388608     // bf16 [512][512]   (524288)
#define WH_OFF    8912896     // f32  [8192][512]  (16777216)
#define HP_OFF    8912896     // f32 overlay after edots/transWh
#define ATTBF_OFF 25690112    // bf16 [4][2048][2048] (33554432)
#define EL_OFF    59244544    // f32  [4][8192]    (131072)
#define SC_OFF    59375616    // f32  [16]
#define FLAG_OFF  59375680    // int
#define CANON_OFF 59375744    // f32  [3152]
// peak ~59.4 MB

#define C_ALP 0
#define C_ARP 256
#define C_ALN 512
#define C_ARN 768
#define C_REL 1024
#define C_ARELP 1084
#define C_ARELN 1094
#define C_LL1 1104
#define C_LR1 1360
#define C_LL2 1616
#define C_LR2 1872
#define C_GAM 2128
#define C_BET 2640

__device__ __forceinline__ float bf_as_f32(unsigned short u) {
    return __uint_as_float(((unsigned)u) << 16);
}
__device__ __forceinline__ float ldf(const void* p, long i, int isf32) {
    return isf32 ? ((const float*)p)[i] : bf_as_f32(((const unsigned short*)p)[i]);
}

// ---------- detect input float dtype (f32 -> flag=1, bf16 -> flag=0) ----------
__global__ void k_detect(const unsigned short* __restrict__ hraw, int* __restrict__ flag) {
    __shared__ float wmax[4];
    int tid = threadIdx.x, lane = tid & 63, wid = tid >> 6;
    float mx = 0.f;
    for (int i = tid; i < 8192; i += 256) {
        float v = fabsf(bf_as_f32(hraw[i]));
        if (v == v && v > mx) mx = v;
    }
    for (int off = 32; off; off >>= 1) mx = fmaxf(mx, __shfl_down(mx, off));
    if (lane == 0) wmax[wid] = mx;
    __syncthreads();
    if (tid == 0) {
        float m = fmaxf(fmaxf(wmax[0], wmax[1]), fmaxf(wmax[2], wmax[3]));
        flag[0] = (m > 1e10f) ? 1 : 0;
    }
}

__global__ __launch_bounds__(256) void k_conv_h(const void* __restrict__ h, const int* __restrict__ flag,
                                                __hip_bfloat16* __restrict__ hbf) {
    int fl = flag[0];
    int idx = blockIdx.x * 256 + threadIdx.x;   // 4194304
    hbf[idx] = __float2bfloat16(ldf(h, idx, fl));
}

__global__ __launch_bounds__(256) void k_conv_W(const void* __restrict__ W, const int* __restrict__ flag,
                                                __hip_bfloat16* __restrict__ Wt) {
    int fl = flag[0];
    int idx = blockIdx.x * 256 + threadIdx.x;   // 262144
    int k = idx >> 9, o = idx & 511;
    Wt[o * 512 + k] = __float2bfloat16(ldf(W, idx, fl));
}

__global__ void k_conv_small(const void* alp, const void* arp, const void* aln, const void* arn,
                             const void* rel, const void* arelp, const void* areln,
                             const void* ll1, const void* lr1, const void* ll2, const void* lr2,
                             const void* gam, const void* bet,
                             const int* __restrict__ flag, float* __restrict__ canon) {
    int fl = flag[0];
    int tid = threadIdx.x;  // 256
    canon[C_ALP + tid] = ldf(alp, tid, fl);
    canon[C_ARP + tid] = ldf(arp, tid, fl);
    canon[C_ALN + tid] = ldf(aln, tid, fl);
    canon[C_ARN + tid] = ldf(arn, tid, fl);
    canon[C_LL1 + tid] = ldf(ll1, tid, fl);
    canon[C_LR1 + tid] = ldf(lr1, tid, fl);
    canon[C_LL2 + tid] = ldf(ll2, tid, fl);
    canon[C_LR2 + tid] = ldf(lr2, tid, fl);
    canon[C_GAM + tid] = ldf(gam, tid, fl);
    canon[C_GAM + 256 + tid] = ldf(gam, 256 + tid, fl);
    canon[C_BET + tid] = ldf(bet, tid, fl);
    canon[C_BET + 256 + tid] = ldf(bet, 256 + tid, fl);
    if (tid < 60) canon[C_REL + tid] = ldf(rel, tid, fl);
    if (tid < 10) { canon[C_ARELP + tid] = ldf(arelp, tid, fl); canon[C_ARELN + tid] = ldf(areln, tid, fl); }
}

__global__ void k_scalars(const float* __restrict__ canon, float* __restrict__ sc) {
    int lane = threadIdx.x;   // 64
    float s1 = 0.f, s2 = 0.f;
    for (int k = lane; k < 256; k += 64) {
        s1 += canon[C_LL1 + k] * canon[C_LR1 + k];
        s2 += canon[C_LL2 + k] * canon[C_LR2 + k];
    }
    for (int off = 32; off; off >>= 1) { s1 += __shfl_down(s1, off); s2 += __shfl_down(s2, off); }
    if (lane == 0) {
        float lam_init = 0.8f - 0.6f * expf(-0.3f);
        sc[0] = expf(s1) - expf(s2) + lam_init;
    }
    if (lane < 6) {
        float p = 0.f, n = 0.f;
        for (int d = 0; d < 10; ++d) {
            float rv = canon[C_REL + lane * 10 + d];
            p += rv * canon[C_ARELP + d];
            n += rv * canon[C_ARELN + d];
        }
        sc[1 + lane] = p;
        sc[7 + lane] = n;
    }
}

// ---------- Wh = h @ W (MFMA 16x16x32 bf16, BM=128 BN=64 BK=32) ----------
__global__ __launch_bounds__(256) void k_gemm_wh(const __hip_bfloat16* __restrict__ A,
                                                 const __hip_bfloat16* __restrict__ Bt,
                                                 float* __restrict__ C) {
    __shared__ short As[128][32];
    __shared__ short Bs[64][32];
    int tid = threadIdx.x, wid = tid >> 6, lane = tid & 63;
    int bm = blockIdx.x * 128, bn = blockIdx.y * 64;
    const short* Ag = (const short*)A;
    const short* Bg = (const short*)Bt;
    f32x4 acc[2][4] = {};
    for (int k0 = 0; k0 < 512; k0 += 32) {
        __syncthreads();
#pragma unroll
        for (int it = 0; it < 2; ++it) {
            int t = it * 256 + tid;
            int row = t >> 2, col8 = (t & 3) * 8;
            *(bf16x8*)&As[row][col8] = *(const bf16x8*)&Ag[(bm + row) * 512 + k0 + col8];
        }
        {
            int row = tid >> 2, col8 = (tid & 3) * 8;
            *(bf16x8*)&Bs[row][col8] = *(const bf16x8*)&Bg[(bn + row) * 512 + k0 + col8];
        }
        __syncthreads();
        int l15 = lane & 15, kh = (lane >> 4) * 8;
        bf16x8 af[2], bfr[4];
#pragma unroll
        for (int m = 0; m < 2; ++m) af[m] = *(const bf16x8*)&As[wid * 32 + m * 16 + l15][kh];
#pragma unroll
        for (int n = 0; n < 4; ++n) bfr[n] = *(const bf16x8*)&Bs[n * 16 + l15][kh];
#pragma unroll
        for (int m = 0; m < 2; ++m)
#pragma unroll
            for (int n = 0; n < 4; ++n)
                acc[m][n] = __builtin_amdgcn_mfma_f32_16x16x32_bf16(af[m], bfr[n], acc[m][n], 0, 0, 0);
    }
    int l15 = lane & 15, rg = (lane >> 4) * 4;
#pragma unroll
    for (int m = 0; m < 2; ++m)
#pragma unroll
        for (int n = 0; n < 4; ++n)
#pragma unroll
            for (int r = 0; r < 4; ++r) {
                int row = bm + wid * 32 + m * 16 + rg + r;
                int col = bn + n * 16 + l15;
                C[row * 512 + col] = acc[m][n][r];
            }
}

// ---------- transpose Wh -> Wht[b][o][j] bf16 ----------
__global__ __launch_bounds__(256) void k_transWh(const float* __restrict__ Wh, __hip_bfloat16* __restrict__ Wht) {
    __shared__ float t[32][33];
    int b = blockIdx.z;
    int o0 = blockIdx.x * 32, j0 = blockIdx.y * 32;
    int tx = threadIdx.x & 31, ty = threadIdx.x >> 5;
#pragma unroll
    for (int r = 0; r < 4; ++r) {
        int j = j0 + ty + r * 8;
        t[ty + r * 8][tx] = Wh[(b * 2048 + j) * 512 + o0 + tx];
    }
    __syncthreads();
#pragma unroll
    for (int r = 0; r < 4; ++r) {
        int o = o0 + ty + r * 8;
        Wht[((long)b * 512 + o) * 2048 + j0 + tx] = __float2bfloat16(t[tx][ty + r * 8]);
    }
}

// ---------- per-row e dots ----------
__global__ __launch_bounds__(256) void k_edots(const float* __restrict__ Wh, const float* __restrict__ canon,
                                               float* __restrict__ el) {
    int wid = threadIdx.x >> 6, lane = threadIdx.x & 63;
    int m = blockIdx.x * 4 + wid;
    float selp = 0.f, serp = 0.f, seln = 0.f, sern = 0.f;
#pragma unroll
    for (int t = 0; t < 4; ++t) {
        int k = t * 64 + lane;
        float wp = Wh[m * 512 + k];
        float wn = Wh[m * 512 + 256 + k];
        selp += wp * canon[C_ALP + k];
        serp += wp * canon[C_ARP + k];
        seln += wn * canon[C_ALN + k];
        sern += wn * canon[C_ARN + k];
    }
    for (int off = 32; off; off >>= 1) {
        selp += __shfl_down(selp, off); serp += __shfl_down(serp, off);
        seln += __shfl_down(seln, off); sern += __shfl_down(sern, off);
    }
    if (lane == 0) {
        el[m] = selp; el[8192 + m] = serp; el[16384 + m] = seln; el[24576 + m] = sern;
    }
}

// ---------- attention rows: dual softmax; write f32 att to d_out AND bf16 att to ws ----------
__global__ __launch_bounds__(256) void k_attn(const int* __restrict__ adj,
                                              const float* __restrict__ el, const float* __restrict__ sc,
                                              float* __restrict__ att_f32,
                                              __hip_bfloat16* __restrict__ att_bf) {
    __shared__ float s_rp[6], s_rn[6], s_lam[1];
    __shared__ float rmp[4], rmn[4], rsp[4], rsn[4];
    int tid = threadIdx.x, lane = tid & 63, wid = tid >> 6;
    if (tid < 6) { s_rp[tid] = sc[1 + tid]; s_rn[tid] = sc[7 + tid]; }
    if (tid == 6) s_lam[0] = sc[0];
    int m = blockIdx.x, b = m >> 11;
    float elp = el[m], eln = el[16384 + m];
    const float* erp = el + 8192 + b * 2048;
    const float* ern = el + 24576 + b * 2048;
    const int* adjr = adj + (long)m * 2048;
    __syncthreads();
    float sp[8], sn[8];
    float mp = NEG_INF_, mn = NEG_INF_;
#pragma unroll
    for (int t = 0; t < 8; ++t) {
        int j = t * 256 + tid;
        int a = adjr[j];
        float ep = elp + erp[j] + s_rp[a];
        float en = eln + ern[j] + s_rn[a];
        ep = ep >= 0.f ? ep : ALPHA_ * ep;
        en = en >= 0.f ? en : ALPHA_ * en;
        sp[t] = a > 0 ? ep : NEG_INF_;
        sn[t] = a > 0 ? en : NEG_INF_;
        mp = fmaxf(mp, sp[t]); mn = fmaxf(mn, sn[t]);
    }
    for (int off = 32; off; off >>= 1) { mp = fmaxf(mp, __shfl_down(mp, off)); mn = fmaxf(mn, __shfl_down(mn, off)); }
    if (lane == 0) { rmp[wid] = mp; rmn[wid] = mn; }
    __syncthreads();
    mp = fmaxf(fmaxf(rmp[0], rmp[1]), fmaxf(rmp[2], rmp[3]));
    mn = fmaxf(fmaxf(rmn[0], rmn[1]), fmaxf(rmn[2], rmn[3]));
    float sump = 0.f, sumn = 0.f;
#pragma unroll
    for (int t = 0; t < 8; ++t) {
        sp[t] = expf(sp[t] - mp);      // masked -> 0; all-masked row -> uniform (matches ref)
        sn[t] = expf(sn[t] - mn);
        sump += sp[t]; sumn += sn[t];
    }
    for (int off = 32; off; off >>= 1) { sump += __shfl_down(sump, off); sumn += __shfl_down(sumn, off); }
    if (lane == 0) { rsp[wid] = sump; rsn[wid] = sumn; }
    __syncthreads();
    sump = rsp[0] + rsp[1] + rsp[2] + rsp[3];
    sumn = rsn[0] + rsn[1] + rsn[2] + rsn[3];
    float ip = 1.0f / sump, inn = 1.0f / sumn;
    float lam = s_lam[0];
#pragma unroll
    for (int t = 0; t < 8; ++t) {
        float v = sp[t] * ip - lam * sn[t] * inn;
        long idx = (long)m * 2048 + t * 256 + tid;
        att_f32[idx] = v;
        att_bf[idx] = __float2bfloat16(v);
    }
}

// ---------- h_prime = attention @ Wh (per batch) ----------
__global__ __launch_bounds__(256) void k_hprime(const __hip_bfloat16* __restrict__ att,
                                                const __hip_bfloat16* __restrict__ Wht,
                                                float* __restrict__ HP) {
    __shared__ short As[128][32];
    __shared__ short Bs[64][32];
    int tid = threadIdx.x, wid = tid >> 6, lane = tid & 63;
    int b = blockIdx.z;
    int bm = blockIdx.x * 128, bn = blockIdx.y * 64;
    const short* Ag = (const short*)(att + (long)b * 2048 * 2048);
    const short* Bg = (const short*)(Wht + (long)b * 512 * 2048);
    f32x4 acc[2][4] = {};
    for (int k0 = 0; k0 < 2048; k0 += 32) {
        __syncthreads();
#pragma unroll
        for (int it = 0; it < 2; ++it) {
            int t = it * 256 + tid;
            int row = t >> 2, col8 = (t & 3) * 8;
            *(bf16x8*)&As[row][col8] = *(const bf16x8*)&Ag[(long)(bm + row) * 2048 + k0 + col8];
        }
        {
            int row = tid >> 2, col8 = (tid & 3) * 8;
            *(bf16x8*)&Bs[row][col8] = *(const bf16x8*)&Bg[(long)(bn + row) * 2048 + k0 + col8];
        }
        __syncthreads();
        int l15 = lane & 15, kh = (lane >> 4) * 8;
        bf16x8 af[2], bfr[4];
#pragma unroll
        for (int m = 0; m < 2; ++m) af[m] = *(const bf16x8*)&As[wid * 32 + m * 16 + l15][kh];
#pragma unroll
        for (int n = 0; n < 4; ++n) bfr[n] = *(const bf16x8*)&Bs[n * 16 + l15][kh];
#pragma unroll
        for (int m = 0; m < 2; ++m)
#pragma unroll
            for (int n = 0; n < 4; ++n)
                acc[m][n] = __builtin_amdgcn_mfma_f32_16x16x32_bf16(af[m], bfr[n], acc[m][n], 0, 0, 0);
    }
    int l15 = lane & 15, rg = (lane >> 4) * 4;
#pragma unroll
    for (int m = 0; m < 2; ++m)
#pragma unroll
        for (int n = 0; n < 4; ++n)
#pragma unroll
            for (int r = 0; r < 4; ++r) {
                int row = bm + wid * 32 + m * 16 + rg + r;
                int col = bn + n * 16 + l15;
                HP[((long)b * 2048 + row) * 512 + col] = acc[m][n][r];
            }
}

// ---------- LayerNorm + gamma/beta + *(1-lam_init) + exact GELU -> f32 ----------
__global__ __launch_bounds__(256) void k_lngelu(const float* __restrict__ HP, const float* __restrict__ canon,
                                                float* __restrict__ out) {
    int wid = threadIdx.x >> 6, lane = threadIdx.x & 63;
    int m = blockIdx.x * 4 + wid;
    float x[8]; float s = 0.f, ss = 0.f;
#pragma unroll
    for (int t = 0; t < 8; ++t) {
        x[t] = HP[m * 512 + t * 64 + lane];
        s += x[t]; ss += x[t] * x[t];
    }
    for (int off = 32; off; off >>= 1) { s += __shfl_xor(s, off); ss += __shfl_xor(ss, off); }
    float mu = s * (1.0f / 512.0f);
    float var = ss * (1.0f / 512.0f) - mu * mu;
    float inv = rsqrtf(fmaxf(var, 0.0f) + EPS_LN_);
    float scale = 1.0f - (0.8f - 0.6f * expf(-0.3f));
#pragma unroll
    for (int t = 0; t < 8; ++t) {
        int k = t * 64 + lane;
        float y = (x[t] - mu) * inv * canon[C_GAM + k] + canon[C_BET + k];
        y *= scale;
        float g = 0.5f * y * (1.0f + erff(y * 0.70710678118654752f));
        out[m * 512 + k] = g;
    }
}

extern "C" void kernel_launch(void* const* d_in, const int* in_sizes, int n_in,
                              void* d_out, int out_size, void* d_ws, size_t ws_size,
                              hipStream_t stream) {
    const void* h   = d_in[0];
    const int*  adj = (const int*)d_in[1];
    const void* W   = d_in[2];
    const void* alp = d_in[3];
    const void* arp = d_in[4];
    const void* aln = d_in[5];
    const void* arn = d_in[6];
    const void* rel = d_in[7];
    const void* arelp = d_in[8];
    const void* areln = d_in[9];
    const void* ll1 = d_in[10];
    const void* lr1 = d_in[11];
    const void* ll2 = d_in[12];
    const void* lr2 = d_in[13];
    const void* gam = d_in[14];
    const void* bet = d_in[15];

    char* ws = (char*)d_ws;
    __hip_bfloat16* hbf   = (__hip_bfloat16*)(ws + HBF_OFF);
    __hip_bfloat16* Wt    = (__hip_bfloat16*)(ws + WT_OFF);
    float*          Wh    = (float*)(ws + WH_OFF);
    __hip_bfloat16* Wht   = (__hip_bfloat16*)(ws + WHT_OFF);
    __hip_bfloat16* attbf = (__hip_bfloat16*)(ws + ATTBF_OFF);
    float*          el    = (float*)(ws + EL_OFF);
    float*          sc    = (float*)(ws + SC_OFF);
    int*            flg   = (int*)(ws + FLAG_OFF);
    float*          can   = (float*)(ws + CANON_OFF);
    float*          HP    = (float*)(ws + HP_OFF);

    float* out_gelu = (float*)d_out;
    float* out_att  = out_gelu + (size_t)B_ * N_ * F_;   // f32 elements

    k_detect<<<1, 256, 0, stream>>>((const unsigned short*)h, flg);
    k_conv_h<<<16384, 256, 0, stream>>>(h, flg, hbf);
    k_conv_W<<<1024, 256, 0, stream>>>(W, flg, Wt);
    k_conv_small<<<1, 256, 0, stream>>>(alp, arp, aln, arn, rel, arelp, areln,
                                        ll1, lr1, ll2, lr2, gam, bet, flg, can);
    k_scalars<<<1, 64, 0, stream>>>(can, sc);
    k_gemm_wh<<<dim3(64, 8), 256, 0, stream>>>(hbf, Wt, Wh);
    k_transWh<<<dim3(16, 64, 4), 256, 0, stream>>>(Wh, Wht);   // overwrites hbf (dead)
    k_edots<<<2048, 256, 0, stream>>>(Wh, can, el);
    k_attn<<<8192, 256, 0, stream>>>(adj, el, sc, out_att, attbf);
    k_hprime<<<dim3(16, 8, 4), 256, 0, stream>>>(attbf, Wht, HP);  // overwrites Wh (dead)
    k_lngelu<<<2048, 256, 0, stream>>>(HP, can, out_gelu);
}